// Round 1
// baseline (302.761 us; speedup 1.0000x reference)
//
#include <hip/hip_runtime.h>
#include <hip/hip_bf16.h>

// pAUC loss:
//   bce(i,j) = -log(clip(sigmoid(pos_i - neg_j), 1e-6, 1-1e-6))
//   out = sum_i topk_j(bce, K=512) / (N_pos * N_neg)
// Key reduction: bce is monotone non-decreasing in neg_j for every row, so the
// per-row top-K columns are the K largest negatives — one global selection.

#define SORT_N 16384      // next pow2 >= n_neg (harness: n_neg = 16384)
#define SORT_T 1024
#define TOPK   512
#define ROWS_PER_BLOCK 128
#define KB_T   256

// ---------- Kernel A: single-block bitonic sort (ascending) of score_neg,
// ---------- emit the top K values (tail of sorted array) to ws.
__global__ __launch_bounds__(SORT_T) void topk_sort_kernel(
    const float* __restrict__ neg, int n_neg,
    float* __restrict__ topk, int k) {
    __shared__ float s[SORT_N];
    const int tid = threadIdx.x;
    for (int i = tid; i < SORT_N; i += SORT_T)
        s[i] = (i < n_neg) ? neg[i] : -3.4e38f;   // pad with -inf-ish
    __syncthreads();
    for (int kk = 2; kk <= SORT_N; kk <<= 1) {
        for (int j = kk >> 1; j > 0; j >>= 1) {
            for (int i = tid; i < SORT_N; i += SORT_T) {
                int ixj = i ^ j;
                if (ixj > i) {
                    float a = s[i], b = s[ixj];
                    bool up = ((i & kk) == 0);        // ascending sub-block
                    if ((a > b) == up) { s[i] = b; s[ixj] = a; }
                }
            }
            __syncthreads();
        }
    }
    for (int t = tid; t < k; t += SORT_T)
        topk[t] = s[SORT_N - k + t];
}

// ---------- Kernel B: per-block partial sum of bce over (rows x topk cols).
__global__ __launch_bounds__(KB_T) void pauc_sum_kernel(
    const float* __restrict__ pos, int n_pos,
    const float* __restrict__ topk, int k,
    float* __restrict__ partials) {
    __shared__ float s_t[TOPK];
    __shared__ float s_red[KB_T / 64];
    const int tid = threadIdx.x;
    for (int i = tid; i < k; i += KB_T) s_t[i] = topk[i];
    __syncthreads();

    const int row0 = blockIdx.x * ROWS_PER_BLOCK;
    float acc = 0.0f;
    for (int r = 0; r < ROWS_PER_BLOCK; ++r) {
        int row = row0 + r;
        if (row >= n_pos) break;
        float pv = pos[row];                 // scalar-cached broadcast
        for (int c = tid; c < k; c += KB_T) {
            float yy = pv - s_t[c];
            float sg = 1.0f / (1.0f + __expf(-yy));
            sg = fminf(fmaxf(sg, 1e-6f), 1.0f - 1e-6f);
            acc -= __logf(sg);
        }
    }
    // wave reduce (wave = 64 on gfx950)
    #pragma unroll
    for (int off = 32; off > 0; off >>= 1) acc += __shfl_down(acc, off, 64);
    const int lane = tid & 63, wave = tid >> 6;
    if (lane == 0) s_red[wave] = acc;
    __syncthreads();
    if (tid == 0) {
        float t = 0.0f;
        #pragma unroll
        for (int w = 0; w < KB_T / 64; ++w) t += s_red[w];
        partials[blockIdx.x] = t;
    }
}

// ---------- Kernel C: reduce block partials, scale, write scalar output.
__global__ __launch_bounds__(64) void finalize_kernel(
    const float* __restrict__ partials, int nb,
    float* __restrict__ out, float inv_denom) {
    float acc = 0.0f;
    for (int i = threadIdx.x; i < nb; i += 64) acc += partials[i];
    #pragma unroll
    for (int off = 32; off > 0; off >>= 1) acc += __shfl_down(acc, off, 64);
    if (threadIdx.x == 0) out[0] = acc * inv_denom;
}

extern "C" void kernel_launch(void* const* d_in, const int* in_sizes, int n_in,
                              void* d_out, int out_size, void* d_ws, size_t ws_size,
                              hipStream_t stream) {
    const float* neg = (const float*)d_in[0];   // score_neg, 16384
    const float* pos = (const float*)d_in[1];   // score_pos, 8192
    const int n_neg = in_sizes[0];
    const int n_pos = in_sizes[1];
    float* out = (float*)d_out;
    float* ws  = (float*)d_ws;

    int k = TOPK; if (k > n_neg) k = n_neg;
    float* topk_buf = ws;            // [0, 512)
    float* partials = ws + TOPK;     // [512, 512+nb)

    const int nb = (n_pos + ROWS_PER_BLOCK - 1) / ROWS_PER_BLOCK;

    topk_sort_kernel<<<1, SORT_T, 0, stream>>>(neg, n_neg, topk_buf, k);
    pauc_sum_kernel<<<nb, KB_T, 0, stream>>>(pos, n_pos, topk_buf, k, partials);
    const float inv_denom = (float)(1.0 / ((double)n_pos * (double)n_neg));
    finalize_kernel<<<1, 64, 0, stream>>>(partials, nb, out, inv_denom);
}

// Round 2
// 77.619 us; speedup vs baseline: 3.9006x; 3.9006x over previous
//
#include <hip/hip_runtime.h>
#include <hip/hip_bf16.h>

// pAUC loss:
//   bce(i,j) = -log(clip(sigmoid(pos_i - neg_j), 1e-6, 1-1e-6))
//   out = sum_i topk_j(bce, K=512) / (N_pos * N_neg)
//
// bce is monotone non-decreasing in neg_j for every row, so each row's top-K
// columns are the K largest negatives — ONE global selection of a multiset
// (order irrelevant: we only sum over it). Radix select, not sort.

#define TOPK   512
#define SEL_T  1024
#define EPT    16                 // SEL_T * EPT = 16384 >= n_neg
#define ROWS_PER_BLOCK 16
#define KB_T   256
// clip(sigmoid,1e-6,1-1e-6) then -log  ==  clamp(bce, -log(1-eps), -log(eps))
#define BCE_LO 1.0000005e-6f
#define BCE_HI 13.8155106f

// ---------- Kernel A: exact top-k multiset via 4-pass byte radix select.
// Keys: monotone float->uint map; all keys register-resident (16/thread).
__global__ __launch_bounds__(SEL_T) void topk_select_kernel(
    const float* __restrict__ neg, int n_neg,
    float* __restrict__ topk, int k) {
    __shared__ unsigned int bins[256];
    __shared__ unsigned int suf[256];
    __shared__ unsigned int bc_prefix, bc_kk;
    __shared__ unsigned int out_gt, out_eq;

    const int tid = threadIdx.x;
    unsigned int keys[EPT];
    #pragma unroll
    for (int t = 0; t < EPT; ++t) {
        int i = t * SEL_T + tid;
        unsigned int key = 0u;              // pad = smallest key, never selected
        if (i < n_neg) {
            unsigned int u = __float_as_uint(neg[i]);
            key = u ^ ((u >> 31) ? 0xFFFFFFFFu : 0x80000000u);
        }
        keys[t] = key;
    }

    unsigned int prefix = 0u, pmask = 0u, kk = (unsigned)k;
    for (int pass = 0; pass < 4; ++pass) {
        const int shift = 24 - 8 * pass;
        if (tid < 256) bins[tid] = 0u;
        __syncthreads();
        #pragma unroll
        for (int t = 0; t < EPT; ++t) {
            unsigned int ky = keys[t];
            if ((ky & pmask) == prefix)
                atomicAdd(&bins[(ky >> shift) & 0xFFu], 1u);
        }
        __syncthreads();
        // suffix sums of bins: wave 0, 4 bins/lane + shfl suffix scan
        if (tid < 64) {
            unsigned int c0 = bins[4*tid], c1 = bins[4*tid+1];
            unsigned int c2 = bins[4*tid+2], c3 = bins[4*tid+3];
            unsigned int part = c0 + c1 + c2 + c3;
            #pragma unroll
            for (int off = 1; off < 64; off <<= 1) {
                unsigned int v = __shfl_down(part, off, 64);
                if (tid + off < 64) part += v;
            }
            suf[4*tid]   = part;
            suf[4*tid+1] = part - c0;
            suf[4*tid+2] = part - c0 - c1;
            suf[4*tid+3] = part - c0 - c1 - c2;
        }
        __syncthreads();
        // exactly one thread satisfies: suf[v] >= kk > suf[v+1]  (suf non-increasing)
        if (tid < 256) {
            unsigned int s_here = suf[tid];
            unsigned int s_next = (tid == 255) ? 0u : suf[tid + 1];
            if (s_here >= kk && s_next < kk) {
                bc_prefix = prefix | ((unsigned)tid << shift);
                bc_kk = kk - s_next;
            }
        }
        __syncthreads();
        prefix = bc_prefix;
        kk = bc_kk;
        pmask = (pmask >> 8) | 0xFF000000u;
    }

    const unsigned int T = prefix;          // exact threshold key
    if (tid == 0) { out_gt = 0u; out_eq = 0u; }
    __syncthreads();
    const unsigned int n_gt = (unsigned)k - kk;   // # strictly-greater selected
    #pragma unroll
    for (int t = 0; t < EPT; ++t) {
        unsigned int ky = keys[t];
        if (ky > T) {
            unsigned int idx = atomicAdd(&out_gt, 1u);
            unsigned int u = (ky >> 31) ? (ky ^ 0x80000000u) : (ky ^ 0xFFFFFFFFu);
            topk[idx] = __uint_as_float(u);
        } else if (ky == T) {
            unsigned int idx = atomicAdd(&out_eq, 1u);
            if (idx < kk) {
                unsigned int u = (ky >> 31) ? (ky ^ 0x80000000u) : (ky ^ 0xFFFFFFFFu);
                topk[n_gt + idx] = __uint_as_float(u);
            }
        }
    }
}

// ---------- Kernel B: partial sums of bce over (16 rows x k cols) per block.
// Top-k values live in registers (2/thread); pos[row] is block-uniform (s_load).
__global__ __launch_bounds__(KB_T) void pauc_sum_kernel(
    const float* __restrict__ pos, int n_pos,
    const float* __restrict__ topk, int k,
    float* __restrict__ partials) {
    const int tid = threadIdx.x;
    const bool c0 = tid < k;
    const bool c1 = tid + KB_T < k;
    const float tv0 = c0 ? topk[tid] : 0.0f;
    const float tv1 = c1 ? topk[tid + KB_T] : 0.0f;
    const int row0 = blockIdx.x * ROWS_PER_BLOCK;
    float acc = 0.0f;
    #pragma unroll
    for (int r = 0; r < ROWS_PER_BLOCK; ++r) {
        int row = row0 + r;
        if (row >= n_pos) break;
        float pv = pos[row];
        // -log(clip(sigmoid(pv - tv))) = clamp(log(1 + exp(tv - pv)))
        float b0 = __logf(1.0f + __expf(tv0 - pv));
        float b1 = __logf(1.0f + __expf(tv1 - pv));
        b0 = fminf(fmaxf(b0, BCE_LO), BCE_HI);
        b1 = fminf(fmaxf(b1, BCE_LO), BCE_HI);
        acc += (c0 ? b0 : 0.0f) + (c1 ? b1 : 0.0f);
    }
    #pragma unroll
    for (int off = 32; off > 0; off >>= 1) acc += __shfl_down(acc, off, 64);
    __shared__ float s_red[KB_T / 64];
    const int lane = tid & 63, wv = tid >> 6;
    if (lane == 0) s_red[wv] = acc;
    __syncthreads();
    if (tid == 0) {
        float t = 0.0f;
        #pragma unroll
        for (int w = 0; w < KB_T / 64; ++w) t += s_red[w];
        partials[blockIdx.x] = t;
    }
}

// ---------- Kernel C: reduce block partials, scale, write scalar output.
__global__ __launch_bounds__(256) void finalize_kernel(
    const float* __restrict__ partials, int nb,
    float* __restrict__ out, float inv_denom) {
    const int tid = threadIdx.x;
    float acc = 0.0f;
    for (int i = tid; i < nb; i += 256) acc += partials[i];
    #pragma unroll
    for (int off = 32; off > 0; off >>= 1) acc += __shfl_down(acc, off, 64);
    __shared__ float s_red[4];
    const int lane = tid & 63, wv = tid >> 6;
    if (lane == 0) s_red[wv] = acc;
    __syncthreads();
    if (tid == 0) out[0] = (s_red[0] + s_red[1] + s_red[2] + s_red[3]) * inv_denom;
}

extern "C" void kernel_launch(void* const* d_in, const int* in_sizes, int n_in,
                              void* d_out, int out_size, void* d_ws, size_t ws_size,
                              hipStream_t stream) {
    const float* neg = (const float*)d_in[0];   // score_neg, 16384
    const float* pos = (const float*)d_in[1];   // score_pos, 8192
    const int n_neg = in_sizes[0];
    const int n_pos = in_sizes[1];
    float* out = (float*)d_out;
    float* ws  = (float*)d_ws;

    int k = TOPK; if (k > n_neg) k = n_neg;
    float* topk_buf = ws;            // [0, 512)
    float* partials = ws + TOPK;     // [512, 512 + nb)

    const int nb = (n_pos + ROWS_PER_BLOCK - 1) / ROWS_PER_BLOCK;   // 512

    topk_select_kernel<<<1, SEL_T, 0, stream>>>(neg, n_neg, topk_buf, k);
    pauc_sum_kernel<<<nb, KB_T, 0, stream>>>(pos, n_pos, topk_buf, k, partials);
    const float inv_denom = (float)(1.0 / ((double)n_pos * (double)n_neg));
    finalize_kernel<<<1, 256, 0, stream>>>(partials, nb, out, inv_denom);
}